// Round 9
// baseline (150.933 us; speedup 1.0000x reference)
//
#include <hip/hip_runtime.h>

// CompositeLoss: fused masked reduction over (2,3,128,128,128).
// R9: exact R3 body (best measured: 41.3 us / FETCH 64.1 MB, 256-thr blocks)
// + XCD-aware d-slab swizzle. Evidence (R3/R6/R7/R8): dur ~= FETCH / 1.5 TB/s
// -> reduce HBM fetch via L2 locality. Round-robin dispatch puts blockIdx%8
// on XCD (blockIdx&7); we give each XCD a contiguous 16-plane d-slab, blocks
// ordered d-major, so the d+1 neighbor plane fetched by plane-d blocks is the
// self-plane of the next blocks on the SAME XCD's L2 (plane pair ~1.8 MB
// < 4 MiB L2). h-neighbors stay within the plane (same XCD).
// 13 partial sums (padded to 16 per block row in d_ws):
//  0:M 1:Mx(d) 2:My(h) 3:Mz(w)  4:Smae 5:Smse 6:Sbg
//  7:Sgx 8:Sgy 9:Sgz  10:Stx 11:Sty 12:Stz
#define NACC 13
#define NPAD 16
#define NBLOCKS 4096   // 2^20 groups / 256
#define NMID 16        // 4096 / 256

__device__ __forceinline__ float4 ld4(const float* p) {
    return *reinterpret_cast<const float4*>(p);
}

__global__ __launch_bounds__(256) void loss_main(
    const float* __restrict__ pred, const float* __restrict__ target,
    const float* __restrict__ mask, float* __restrict__ partials)
{
    float acc[NACC];
#pragma unroll
    for (int k = 0; k < NACC; ++k) acc[k] = 0.f;

    const float4 z4 = make_float4(0.f, 0.f, 0.f, 0.f);

    // XCD d-slab swizzle: xcd = blockIdx&7 owns d in [16*xcd, 16*xcd+16).
    // local = blockIdx>>3 (0..511): d_local = local>>5 (plane-major order),
    // r = local&31 -> within-plane block. Thread q = r*256+tid covers
    // (b, h, w4): w4 = q&31, h = (q>>5)&127, b = q>>12.
    const int xcd     = blockIdx.x & 7;
    const int local   = blockIdx.x >> 3;
    const int d       = (xcd << 4) + (local >> 5);
    const int q       = ((local & 31) << 8) + threadIdx.x;
    const int w4      = q & 31;
    const int h       = (q >> 5) & 127;
    const int b       = q >> 12;
    const int w       = w4 << 2;
    const int mb  = b * 2097152 + d * 16384 + h * 128 + w; // mask index
    const int pb0 = b * 6291456 + d * 16384 + h * 128 + w; // pred/target base
    const bool hw = w4 < 31, hh = h < 127, hd = d < 127;

    const float4 m0  = ld4(mask + mb);
    const float  m4w = hw ? mask[mb + 4] : 0.f;
    const float4 mh  = hh ? ld4(mask + mb + 128)   : z4;
    const float4 md  = hd ? ld4(mask + mb + 16384) : z4;

    // pairwise mins (binary mask -> AND); zero-filled neighbors kill OOB terms
    const float mz0 = fminf(m0.x, m0.y), mz1 = fminf(m0.y, m0.z),
                mz2 = fminf(m0.z, m0.w), mz3 = fminf(m0.w, m4w);
    const float my0 = fminf(m0.x, mh.x), my1 = fminf(m0.y, mh.y),
                my2 = fminf(m0.z, mh.z), my3 = fminf(m0.w, mh.w);
    const float mx0 = fminf(m0.x, md.x), mx1 = fminf(m0.y, md.y),
                mx2 = fminf(m0.z, md.z), mx3 = fminf(m0.w, md.w);

    acc[0] = m0.x + m0.y + m0.z + m0.w;
    acc[1] = mx0 + mx1 + mx2 + mx3;
    acc[2] = my0 + my1 + my2 + my3;
    acc[3] = mz0 + mz1 + mz2 + mz3;

#pragma unroll
    for (int c = 0; c < 3; ++c) {
        const int pb = pb0 + c * 2097152;
        const float4 p0 = ld4(pred + pb);
        const float4 t0 = ld4(target + pb);
        float p4 = 0.f, t4 = 0.f;
        if (hw) { p4 = pred[pb + 4]; t4 = target[pb + 4]; }
        const float4 ph = hh ? ld4(pred + pb + 128)     : z4;
        const float4 th = hh ? ld4(target + pb + 128)   : z4;
        const float4 pd = hd ? ld4(pred + pb + 16384)   : z4;
        const float4 td = hd ? ld4(target + pb + 16384) : z4;

        const float e0x = p0.x - t0.x, e0y = p0.y - t0.y,
                    e0z = p0.z - t0.z, e0w = p0.w - t0.w;
        const float e4  = p4 - t4;

        acc[4] += fabsf(e0x)*m0.x + fabsf(e0y)*m0.y
                + fabsf(e0z)*m0.z + fabsf(e0w)*m0.w;
        acc[5] += e0x*e0x*m0.x + e0y*e0y*m0.y
                + e0z*e0z*m0.z + e0w*e0w*m0.w;
        acc[6] += fabsf(p0.x)*(1.f-m0.x) + fabsf(p0.y)*(1.f-m0.y)
                + fabsf(p0.z)*(1.f-m0.z) + fabsf(p0.w)*(1.f-m0.w);

        // W direction (reference dz)
        acc[9]  += fabsf(e0y-e0x)*mz0 + fabsf(e0z-e0y)*mz1
                 + fabsf(e0w-e0z)*mz2 + fabsf(e4 -e0w)*mz3;
        acc[12] += fabsf(p0.y-p0.x)*mz0 + fabsf(p0.z-p0.y)*mz1
                 + fabsf(p0.w-p0.z)*mz2 + fabsf(p4  -p0.w)*mz3;

        // H direction (reference dy)
        acc[8]  += fabsf((ph.x-th.x)-e0x)*my0 + fabsf((ph.y-th.y)-e0y)*my1
                 + fabsf((ph.z-th.z)-e0z)*my2 + fabsf((ph.w-th.w)-e0w)*my3;
        acc[11] += fabsf(ph.x-p0.x)*my0 + fabsf(ph.y-p0.y)*my1
                 + fabsf(ph.z-p0.z)*my2 + fabsf(ph.w-p0.w)*my3;

        // D direction (reference dx)
        acc[7]  += fabsf((pd.x-td.x)-e0x)*mx0 + fabsf((pd.y-td.y)-e0y)*mx1
                 + fabsf((pd.z-td.z)-e0z)*mx2 + fabsf((pd.w-td.w)-e0w)*mx3;
        acc[10] += fabsf(pd.x-p0.x)*mx0 + fabsf(pd.y-p0.y)*mx1
                 + fabsf(pd.z-p0.z)*mx2 + fabsf(pd.w-p0.w)*mx3;
    }

    // wave (64) shuffle reduce -> LDS -> padded per-block row [block][16]
    const int lane = threadIdx.x & 63;
    const int wave = threadIdx.x >> 6;
    __shared__ float red[4][NACC];
#pragma unroll
    for (int k = 0; k < NACC; ++k) {
        float v = acc[k];
        for (int o = 32; o > 0; o >>= 1) v += __shfl_down(v, o, 64);
        if (lane == 0) red[wave][k] = v;
    }
    __syncthreads();
    if (threadIdx.x < NPAD) {
        const int k = threadIdx.x;
        const float v = (k < NACC)
            ? red[0][k] + red[1][k] + red[2][k] + red[3][k] : 0.f;
        partials[blockIdx.x * NPAD + k] = v;  // d_ws is poisoned: write all 16
    }
}

// Level 1: 16 blocks x 256 threads; thread r reads row r (4 independent
// float4), block-reduces 256 rows -> 1 row.
__global__ __launch_bounds__(256) void loss_mid(
    const float* __restrict__ partials, float* __restrict__ mid)
{
    const int r = blockIdx.x * 256 + threadIdx.x;   // exactly covers 4096
    const float* row = partials + r * NPAD;
    const float4 r0 = ld4(row);     const float4 r1 = ld4(row + 4);
    const float4 r2 = ld4(row + 8); const float4 r3 = ld4(row + 12);
    float acc[NPAD] = {r0.x, r0.y, r0.z, r0.w, r1.x, r1.y, r1.z, r1.w,
                       r2.x, r2.y, r2.z, r2.w, r3.x, r3.y, r3.z, r3.w};

    const int lane = threadIdx.x & 63;
    const int wave = threadIdx.x >> 6;
    __shared__ float red[4][NPAD];
#pragma unroll
    for (int k = 0; k < NPAD; ++k) {
        float v = acc[k];
        for (int o = 32; o > 0; o >>= 1) v += __shfl_down(v, o, 64);
        if (lane == 0) red[wave][k] = v;
    }
    __syncthreads();
    if (threadIdx.x < NPAD) {
        const int k = threadIdx.x;
        mid[blockIdx.x * NPAD + k] =
            red[0][k] + red[1][k] + red[2][k] + red[3][k];
    }
}

// Level 2: one wave; lane l reads mid row l (16 rows), shuffle-reduce,
// lane 0 does the scalar epilogue.
__global__ __launch_bounds__(64) void loss_final(
    const float* __restrict__ mid, float* __restrict__ out)
{
    const int lane = threadIdx.x;
    float acc[NPAD];
#pragma unroll
    for (int k = 0; k < NPAD; ++k) acc[k] = 0.f;
    if (lane < NMID) {
        const float* row = mid + lane * NPAD;
        const float4 r0 = ld4(row);     const float4 r1 = ld4(row + 4);
        const float4 r2 = ld4(row + 8); const float4 r3 = ld4(row + 12);
        acc[0] = r0.x;  acc[1] = r0.y;  acc[2] = r0.z;  acc[3] = r0.w;
        acc[4] = r1.x;  acc[5] = r1.y;  acc[6] = r1.z;  acc[7] = r1.w;
        acc[8] = r2.x;  acc[9] = r2.y;  acc[10] = r2.z; acc[11] = r2.w;
        acc[12] = r3.x; acc[13] = r3.y; acc[14] = r3.z; acc[15] = r3.w;
    }
#pragma unroll
    for (int k = 0; k < NACC; ++k) {
        for (int o = 32; o > 0; o >>= 1) acc[k] += __shfl_down(acc[k], o, 64);
    }
    if (lane == 0) {
        const float EPS = 1e-8f;
        const float M = acc[0], Mx = acc[1], My = acc[2], Mz = acc[3];
        float loss = (acc[4] + acc[5]) / (3.f * M + EPS);   // W_MAE=1, W_MSE=1
        loss += 0.1f   * (acc[7] / (3.f*Mx + EPS) + acc[8] / (3.f*My + EPS)
                        + acc[9] / (3.f*Mz + EPS));
        loss += 0.002f * (acc[10] / (3.f*Mx + EPS) + acc[11] / (3.f*My + EPS)
                        + acc[12] / (3.f*Mz + EPS));
        const float inv = 4194304.f - M;  // B*D*H*W - M
        loss += 0.15f * acc[6] / (3.f * inv + EPS);
        out[0] = loss;
    }
}

extern "C" void kernel_launch(void* const* d_in, const int* in_sizes, int n_in,
                              void* d_out, int out_size, void* d_ws, size_t ws_size,
                              hipStream_t stream) {
    const float* pred   = (const float*)d_in[0];
    const float* target = (const float*)d_in[1];
    const float* mask   = (const float*)d_in[2];
    float* out      = (float*)d_out;
    float* partials = (float*)d_ws;                 // 4096*16 floats = 256 KiB
    float* mid      = partials + NBLOCKS * NPAD;    // 16*16 floats

    loss_main<<<NBLOCKS, 256, 0, stream>>>(pred, target, mask, partials);
    loss_mid<<<NMID, 256, 0, stream>>>(partials, mid);
    loss_final<<<1, 64, 0, stream>>>(mid, out);
}

// Round 10
// 147.896 us; speedup vs baseline: 1.0205x; 1.0205x over previous
//
#include <hip/hip_runtime.h>

// CompositeLoss: fused masked reduction over (2,3,128,128,128).
// R10: exact R3 mapping (best measured: 41.3 us) with BRANCH-FREE loads.
// All 21 per-thread loads are unconditional: boundary neighbors clamp their
// OFFSET to stay in-bounds (oh/od/ow = 0 at the edge) and the corresponding
// pairwise-min masks are multiplied by a 0/1 boundary flag, so the garbage
// (but finite, in-bounds) values are annihilated by zero masks. This removes
// the exec-mask branches that fragmented the wave's load burst into ~6
// serialized phases -> all loads in flight at once.
// 13 partial sums (padded to 16 per block row in d_ws):
//  0:M 1:Mx(d) 2:My(h) 3:Mz(w)  4:Smae 5:Smse 6:Sbg
//  7:Sgx 8:Sgy 9:Sgz  10:Stx 11:Sty 12:Stz
#define NACC 13
#define NPAD 16
#define NBLOCKS 4096   // 2^20 groups / 256
#define NMID 16        // 4096 / 256

__device__ __forceinline__ float4 ld4(const float* p) {
    return *reinterpret_cast<const float4*>(p);
}

__global__ __launch_bounds__(256) void loss_main(
    const float* __restrict__ pred, const float* __restrict__ target,
    const float* __restrict__ mask, float* __restrict__ partials)
{
    float acc[NACC];
#pragma unroll
    for (int k = 0; k < NACC; ++k) acc[k] = 0.f;

    // one group per thread: group = (b, d, h, w4); mapping identical to R3
    const int g  = blockIdx.x * 256 + threadIdx.x;
    const int w4 = g & 31;
    const int h  = (g >> 5) & 127;
    const int d  = (g >> 12) & 127;
    const int b  = g >> 19;
    const int w  = w4 << 2;
    const int mb  = b * 2097152 + d * 16384 + h * 128 + w; // mask index
    const int pb0 = b * 6291456 + d * 16384 + h * 128 + w; // pred/target base

    // boundary: clamp offsets in-bounds; flags zero the affected masks
    const float wv = (w4 < 31) ? 1.f : 0.f;
    const float hv = (h < 127) ? 1.f : 0.f;
    const float dv = (d < 127) ? 1.f : 0.f;
    const int ow = (w4 < 31) ? 4     : 0;
    const int oh = (h < 127) ? 128   : 0;
    const int od = (d < 127) ? 16384 : 0;

    // ---- all loads unconditional: one burst, max MLP ----
    const float4 m0  = ld4(mask + mb);
    const float4 mh  = ld4(mask + mb + oh);
    const float4 md  = ld4(mask + mb + od);
    const float  m4w = mask[mb + ow];

    // pairwise mins (binary mask -> AND); boundary flags kill clamped terms
    const float mz0 = fminf(m0.x, m0.y), mz1 = fminf(m0.y, m0.z),
                mz2 = fminf(m0.z, m0.w), mz3 = fminf(m0.w, m4w) * wv;
    const float my0 = fminf(m0.x, mh.x) * hv, my1 = fminf(m0.y, mh.y) * hv,
                my2 = fminf(m0.z, mh.z) * hv, my3 = fminf(m0.w, mh.w) * hv;
    const float mx0 = fminf(m0.x, md.x) * dv, mx1 = fminf(m0.y, md.y) * dv,
                mx2 = fminf(m0.z, md.z) * dv, mx3 = fminf(m0.w, md.w) * dv;

    acc[0] = m0.x + m0.y + m0.z + m0.w;
    acc[1] = mx0 + mx1 + mx2 + mx3;
    acc[2] = my0 + my1 + my2 + my3;
    acc[3] = mz0 + mz1 + mz2 + mz3;

#pragma unroll
    for (int c = 0; c < 3; ++c) {
        const int pb = pb0 + c * 2097152;
        const float4 p0 = ld4(pred + pb);
        const float4 t0 = ld4(target + pb);
        const float  p4 = pred[pb + ow];
        const float  t4 = target[pb + ow];
        const float4 ph = ld4(pred + pb + oh);
        const float4 th = ld4(target + pb + oh);
        const float4 pd = ld4(pred + pb + od);
        const float4 td = ld4(target + pb + od);

        const float e0x = p0.x - t0.x, e0y = p0.y - t0.y,
                    e0z = p0.z - t0.z, e0w = p0.w - t0.w;
        const float e4  = p4 - t4;

        acc[4] += fabsf(e0x)*m0.x + fabsf(e0y)*m0.y
                + fabsf(e0z)*m0.z + fabsf(e0w)*m0.w;
        acc[5] += e0x*e0x*m0.x + e0y*e0y*m0.y
                + e0z*e0z*m0.z + e0w*e0w*m0.w;
        acc[6] += fabsf(p0.x)*(1.f-m0.x) + fabsf(p0.y)*(1.f-m0.y)
                + fabsf(p0.z)*(1.f-m0.z) + fabsf(p0.w)*(1.f-m0.w);

        // W direction (reference dz); mz3=0 at w-boundary kills e4 garbage
        acc[9]  += fabsf(e0y-e0x)*mz0 + fabsf(e0z-e0y)*mz1
                 + fabsf(e0w-e0z)*mz2 + fabsf(e4 -e0w)*mz3;
        acc[12] += fabsf(p0.y-p0.x)*mz0 + fabsf(p0.z-p0.y)*mz1
                 + fabsf(p0.w-p0.z)*mz2 + fabsf(p4  -p0.w)*mz3;

        // H direction (reference dy); my*=0 at h-boundary
        acc[8]  += fabsf((ph.x-th.x)-e0x)*my0 + fabsf((ph.y-th.y)-e0y)*my1
                 + fabsf((ph.z-th.z)-e0z)*my2 + fabsf((ph.w-th.w)-e0w)*my3;
        acc[11] += fabsf(ph.x-p0.x)*my0 + fabsf(ph.y-p0.y)*my1
                 + fabsf(ph.z-p0.z)*my2 + fabsf(ph.w-p0.w)*my3;

        // D direction (reference dx); mx*=0 at d-boundary
        acc[7]  += fabsf((pd.x-td.x)-e0x)*mx0 + fabsf((pd.y-td.y)-e0y)*mx1
                 + fabsf((pd.z-td.z)-e0z)*mx2 + fabsf((pd.w-td.w)-e0w)*mx3;
        acc[10] += fabsf(pd.x-p0.x)*mx0 + fabsf(pd.y-p0.y)*mx1
                 + fabsf(pd.z-p0.z)*mx2 + fabsf(pd.w-p0.w)*mx3;
    }

    // wave (64) shuffle reduce -> LDS -> padded per-block row [block][16]
    const int lane = threadIdx.x & 63;
    const int wave = threadIdx.x >> 6;
    __shared__ float red[4][NACC];
#pragma unroll
    for (int k = 0; k < NACC; ++k) {
        float v = acc[k];
        for (int o = 32; o > 0; o >>= 1) v += __shfl_down(v, o, 64);
        if (lane == 0) red[wave][k] = v;
    }
    __syncthreads();
    if (threadIdx.x < NPAD) {
        const int k = threadIdx.x;
        const float v = (k < NACC)
            ? red[0][k] + red[1][k] + red[2][k] + red[3][k] : 0.f;
        partials[blockIdx.x * NPAD + k] = v;  // d_ws is poisoned: write all 16
    }
}

// Level 1: 16 blocks x 256 threads; thread r reads row r (4 independent
// float4), block-reduces 256 rows -> 1 row.
__global__ __launch_bounds__(256) void loss_mid(
    const float* __restrict__ partials, float* __restrict__ mid)
{
    const int r = blockIdx.x * 256 + threadIdx.x;   // exactly covers 4096
    const float* row = partials + r * NPAD;
    const float4 r0 = ld4(row);     const float4 r1 = ld4(row + 4);
    const float4 r2 = ld4(row + 8); const float4 r3 = ld4(row + 12);
    float acc[NPAD] = {r0.x, r0.y, r0.z, r0.w, r1.x, r1.y, r1.z, r1.w,
                       r2.x, r2.y, r2.z, r2.w, r3.x, r3.y, r3.z, r3.w};

    const int lane = threadIdx.x & 63;
    const int wave = threadIdx.x >> 6;
    __shared__ float red[4][NPAD];
#pragma unroll
    for (int k = 0; k < NPAD; ++k) {
        float v = acc[k];
        for (int o = 32; o > 0; o >>= 1) v += __shfl_down(v, o, 64);
        if (lane == 0) red[wave][k] = v;
    }
    __syncthreads();
    if (threadIdx.x < NPAD) {
        const int k = threadIdx.x;
        mid[blockIdx.x * NPAD + k] =
            red[0][k] + red[1][k] + red[2][k] + red[3][k];
    }
}

// Level 2: one wave; lane l reads mid row l (16 rows), shuffle-reduce,
// lane 0 does the scalar epilogue.
__global__ __launch_bounds__(64) void loss_final(
    const float* __restrict__ mid, float* __restrict__ out)
{
    const int lane = threadIdx.x;
    float acc[NPAD];
#pragma unroll
    for (int k = 0; k < NPAD; ++k) acc[k] = 0.f;
    if (lane < NMID) {
        const float* row = mid + lane * NPAD;
        const float4 r0 = ld4(row);     const float4 r1 = ld4(row + 4);
        const float4 r2 = ld4(row + 8); const float4 r3 = ld4(row + 12);
        acc[0] = r0.x;  acc[1] = r0.y;  acc[2] = r0.z;  acc[3] = r0.w;
        acc[4] = r1.x;  acc[5] = r1.y;  acc[6] = r1.z;  acc[7] = r1.w;
        acc[8] = r2.x;  acc[9] = r2.y;  acc[10] = r2.z; acc[11] = r2.w;
        acc[12] = r3.x; acc[13] = r3.y; acc[14] = r3.z; acc[15] = r3.w;
    }
#pragma unroll
    for (int k = 0; k < NACC; ++k) {
        for (int o = 32; o > 0; o >>= 1) acc[k] += __shfl_down(acc[k], o, 64);
    }
    if (lane == 0) {
        const float EPS = 1e-8f;
        const float M = acc[0], Mx = acc[1], My = acc[2], Mz = acc[3];
        float loss = (acc[4] + acc[5]) / (3.f * M + EPS);   // W_MAE=1, W_MSE=1
        loss += 0.1f   * (acc[7] / (3.f*Mx + EPS) + acc[8] / (3.f*My + EPS)
                        + acc[9] / (3.f*Mz + EPS));
        loss += 0.002f * (acc[10] / (3.f*Mx + EPS) + acc[11] / (3.f*My + EPS)
                        + acc[12] / (3.f*Mz + EPS));
        const float inv = 4194304.f - M;  // B*D*H*W - M
        loss += 0.15f * acc[6] / (3.f * inv + EPS);
        out[0] = loss;
    }
}

extern "C" void kernel_launch(void* const* d_in, const int* in_sizes, int n_in,
                              void* d_out, int out_size, void* d_ws, size_t ws_size,
                              hipStream_t stream) {
    const float* pred   = (const float*)d_in[0];
    const float* target = (const float*)d_in[1];
    const float* mask   = (const float*)d_in[2];
    float* out      = (float*)d_out;
    float* partials = (float*)d_ws;                 // 4096*16 floats = 256 KiB
    float* mid      = partials + NBLOCKS * NPAD;    // 16*16 floats

    loss_main<<<NBLOCKS, 256, 0, stream>>>(pred, target, mask, partials);
    loss_mid<<<NMID, 256, 0, stream>>>(partials, mid);
    loss_final<<<1, 64, 0, stream>>>(mid, out);
}

// Round 11
// 143.809 us; speedup vs baseline: 1.0495x; 1.0284x over previous
//
#include <hip/hip_runtime.h>

// CompositeLoss: fused masked reduction over (2,3,128,128,128).
// R11: R10 body with (a) W-neighbor via __shfl_down instead of 7 scalar
// global loads -- the w+4 value is the next lane's w4-group first element;
// lanes with w4==31 (lane 31/63) get a wrong-row value but wv=0 already
// zeroes mz3, the only consumer. VMEM insts 28->21. (b) per-wave partials:
// no __syncthreads / no LDS in loss_main -- each wave shuffle-reduces and
// retires independently (removes 4-wave convoying at block end).
// Partial rows: 4 waves/block * 4096 blocks = 16384 rows of 16.
//  0:M 1:Mx(d) 2:My(h) 3:Mz(w)  4:Smae 5:Smse 6:Sbg
//  7:Sgx 8:Sgy 9:Sgz  10:Stx 11:Sty 12:Stz
#define NACC 13
#define NPAD 16
#define NBLOCKS 4096   // 2^20 groups / 256
#define NROWS 16384    // NBLOCKS * 4 waves
#define NMID 64        // 16384 / 256

__device__ __forceinline__ float4 ld4(const float* p) {
    return *reinterpret_cast<const float4*>(p);
}

__global__ __launch_bounds__(256) void loss_main(
    const float* __restrict__ pred, const float* __restrict__ target,
    const float* __restrict__ mask, float* __restrict__ partials)
{
    float acc[NACC];
#pragma unroll
    for (int k = 0; k < NACC; ++k) acc[k] = 0.f;

    // one group per thread: group = (b, d, h, w4); mapping identical to R3
    const int g  = blockIdx.x * 256 + threadIdx.x;
    const int w4 = g & 31;
    const int h  = (g >> 5) & 127;
    const int d  = (g >> 12) & 127;
    const int b  = g >> 19;
    const int w  = w4 << 2;
    const int mb  = b * 2097152 + d * 16384 + h * 128 + w; // mask index
    const int pb0 = b * 6291456 + d * 16384 + h * 128 + w; // pred/target base

    // boundary: clamp offsets in-bounds; flags zero the affected masks
    const float wv = (w4 < 31) ? 1.f : 0.f;
    const float hv = (h < 127) ? 1.f : 0.f;
    const float dv = (d < 127) ? 1.f : 0.f;
    const int oh = (h < 127) ? 128   : 0;
    const int od = (d < 127) ? 16384 : 0;

    // ---- all loads unconditional; W-neighbor comes from the next lane ----
    const float4 m0  = ld4(mask + mb);
    const float4 mh  = ld4(mask + mb + oh);
    const float4 md  = ld4(mask + mb + od);
    const float  m4w = __shfl_down(m0.x, 1, 64);  // lane w4=31: garbage, wv=0

    // pairwise mins (binary mask -> AND); boundary flags kill clamped terms
    const float mz0 = fminf(m0.x, m0.y), mz1 = fminf(m0.y, m0.z),
                mz2 = fminf(m0.z, m0.w), mz3 = fminf(m0.w, m4w) * wv;
    const float my0 = fminf(m0.x, mh.x) * hv, my1 = fminf(m0.y, mh.y) * hv,
                my2 = fminf(m0.z, mh.z) * hv, my3 = fminf(m0.w, mh.w) * hv;
    const float mx0 = fminf(m0.x, md.x) * dv, mx1 = fminf(m0.y, md.y) * dv,
                mx2 = fminf(m0.z, md.z) * dv, mx3 = fminf(m0.w, md.w) * dv;

    acc[0] = m0.x + m0.y + m0.z + m0.w;
    acc[1] = mx0 + mx1 + mx2 + mx3;
    acc[2] = my0 + my1 + my2 + my3;
    acc[3] = mz0 + mz1 + mz2 + mz3;

#pragma unroll
    for (int c = 0; c < 3; ++c) {
        const int pb = pb0 + c * 2097152;
        const float4 p0 = ld4(pred + pb);
        const float4 t0 = ld4(target + pb);
        const float4 ph = ld4(pred + pb + oh);
        const float4 th = ld4(target + pb + oh);
        const float4 pd = ld4(pred + pb + od);
        const float4 td = ld4(target + pb + od);
        const float  p4 = __shfl_down(p0.x, 1, 64);  // w-neighbor from lane+1
        const float  t4 = __shfl_down(t0.x, 1, 64);

        const float e0x = p0.x - t0.x, e0y = p0.y - t0.y,
                    e0z = p0.z - t0.z, e0w = p0.w - t0.w;
        const float e4  = p4 - t4;

        acc[4] += fabsf(e0x)*m0.x + fabsf(e0y)*m0.y
                + fabsf(e0z)*m0.z + fabsf(e0w)*m0.w;
        acc[5] += e0x*e0x*m0.x + e0y*e0y*m0.y
                + e0z*e0z*m0.z + e0w*e0w*m0.w;
        acc[6] += fabsf(p0.x)*(1.f-m0.x) + fabsf(p0.y)*(1.f-m0.y)
                + fabsf(p0.z)*(1.f-m0.z) + fabsf(p0.w)*(1.f-m0.w);

        // W direction (reference dz); mz3=0 at w-boundary kills shfl garbage
        acc[9]  += fabsf(e0y-e0x)*mz0 + fabsf(e0z-e0y)*mz1
                 + fabsf(e0w-e0z)*mz2 + fabsf(e4 -e0w)*mz3;
        acc[12] += fabsf(p0.y-p0.x)*mz0 + fabsf(p0.z-p0.y)*mz1
                 + fabsf(p0.w-p0.z)*mz2 + fabsf(p4  -p0.w)*mz3;

        // H direction (reference dy); my*=0 at h-boundary
        acc[8]  += fabsf((ph.x-th.x)-e0x)*my0 + fabsf((ph.y-th.y)-e0y)*my1
                 + fabsf((ph.z-th.z)-e0z)*my2 + fabsf((ph.w-th.w)-e0w)*my3;
        acc[11] += fabsf(ph.x-p0.x)*my0 + fabsf(ph.y-p0.y)*my1
                 + fabsf(ph.z-p0.z)*my2 + fabsf(ph.w-p0.w)*my3;

        // D direction (reference dx); mx*=0 at d-boundary
        acc[7]  += fabsf((pd.x-td.x)-e0x)*mx0 + fabsf((pd.y-td.y)-e0y)*mx1
                 + fabsf((pd.z-td.z)-e0z)*mx2 + fabsf((pd.w-td.w)-e0w)*mx3;
        acc[10] += fabsf(pd.x-p0.x)*mx0 + fabsf(pd.y-p0.y)*mx1
                 + fabsf(pd.z-p0.z)*mx2 + fabsf(pd.w-p0.w)*mx3;
    }

    // per-wave shuffle reduce -> own partials row; NO __syncthreads:
    // each wave retires as soon as its own tail drains.
    const int lane = threadIdx.x & 63;
    const int wave = threadIdx.x >> 6;
    float mine = 0.f;   // lane k (<16) ends up holding total of acc[k]
#pragma unroll
    for (int k = 0; k < NACC; ++k) {
        float v = acc[k];
        for (int o = 32; o > 0; o >>= 1) v += __shfl_down(v, o, 64);
        const float tot = __shfl(v, 0, 64);
        if (lane == k) mine = tot;
    }
    if (lane < NPAD)
        partials[(blockIdx.x * 4 + wave) * NPAD + lane] = mine; // pad rows=0
}

// Level 1: 64 blocks x 256 threads; thread r reads row r (4 independent
// float4), block-reduces 256 rows -> 1 row.
__global__ __launch_bounds__(256) void loss_mid(
    const float* __restrict__ partials, float* __restrict__ mid)
{
    const int r = blockIdx.x * 256 + threadIdx.x;   // exactly covers 16384
    const float* row = partials + r * NPAD;
    const float4 r0 = ld4(row);     const float4 r1 = ld4(row + 4);
    const float4 r2 = ld4(row + 8); const float4 r3 = ld4(row + 12);
    float acc[NPAD] = {r0.x, r0.y, r0.z, r0.w, r1.x, r1.y, r1.z, r1.w,
                       r2.x, r2.y, r2.z, r2.w, r3.x, r3.y, r3.z, r3.w};

    const int lane = threadIdx.x & 63;
    const int wave = threadIdx.x >> 6;
    __shared__ float red[4][NPAD];
#pragma unroll
    for (int k = 0; k < NPAD; ++k) {
        float v = acc[k];
        for (int o = 32; o > 0; o >>= 1) v += __shfl_down(v, o, 64);
        if (lane == 0) red[wave][k] = v;
    }
    __syncthreads();
    if (threadIdx.x < NPAD) {
        const int k = threadIdx.x;
        mid[blockIdx.x * NPAD + k] =
            red[0][k] + red[1][k] + red[2][k] + red[3][k];
    }
}

// Level 2: one wave; lane l reads mid row l (64 rows), shuffle-reduce,
// lane 0 does the scalar epilogue.
__global__ __launch_bounds__(64) void loss_final(
    const float* __restrict__ mid, float* __restrict__ out)
{
    const int lane = threadIdx.x;
    float acc[NPAD];
    {
        const float* row = mid + lane * NPAD;   // lane < 64 == NMID
        const float4 r0 = ld4(row);     const float4 r1 = ld4(row + 4);
        const float4 r2 = ld4(row + 8); const float4 r3 = ld4(row + 12);
        acc[0] = r0.x;  acc[1] = r0.y;  acc[2] = r0.z;  acc[3] = r0.w;
        acc[4] = r1.x;  acc[5] = r1.y;  acc[6] = r1.z;  acc[7] = r1.w;
        acc[8] = r2.x;  acc[9] = r2.y;  acc[10] = r2.z; acc[11] = r2.w;
        acc[12] = r3.x; acc[13] = r3.y; acc[14] = r3.z; acc[15] = r3.w;
    }
#pragma unroll
    for (int k = 0; k < NACC; ++k) {
        for (int o = 32; o > 0; o >>= 1) acc[k] += __shfl_down(acc[k], o, 64);
    }
    if (lane == 0) {
        const float EPS = 1e-8f;
        const float M = acc[0], Mx = acc[1], My = acc[2], Mz = acc[3];
        float loss = (acc[4] + acc[5]) / (3.f * M + EPS);   // W_MAE=1, W_MSE=1
        loss += 0.1f   * (acc[7] / (3.f*Mx + EPS) + acc[8] / (3.f*My + EPS)
                        + acc[9] / (3.f*Mz + EPS));
        loss += 0.002f * (acc[10] / (3.f*Mx + EPS) + acc[11] / (3.f*My + EPS)
                        + acc[12] / (3.f*Mz + EPS));
        const float inv = 4194304.f - M;  // B*D*H*W - M
        loss += 0.15f * acc[6] / (3.f * inv + EPS);
        out[0] = loss;
    }
}

extern "C" void kernel_launch(void* const* d_in, const int* in_sizes, int n_in,
                              void* d_out, int out_size, void* d_ws, size_t ws_size,
                              hipStream_t stream) {
    const float* pred   = (const float*)d_in[0];
    const float* target = (const float*)d_in[1];
    const float* mask   = (const float*)d_in[2];
    float* out      = (float*)d_out;
    float* partials = (float*)d_ws;                 // 16384*16 floats = 1 MiB
    float* mid      = partials + NROWS * NPAD;      // 64*16 floats

    loss_main<<<NBLOCKS, 256, 0, stream>>>(pred, target, mask, partials);
    loss_mid<<<NMID, 256, 0, stream>>>(partials, mid);
    loss_final<<<1, 64, 0, stream>>>(mid, out);
}